// Round 10
// baseline (155.625 us; speedup 1.0000x reference)
//
#include <hip/hip_runtime.h>
#include <math.h>

#define NH 8
#define HD 64
#define NTOK 1024
#define CIN 256
#define HIDDEN 512
#define O3 1536
#define BATCH 8
#define ATT_SCALE 0.125f
#define LOG2E 1.44269504f

typedef unsigned short u16;
typedef __attribute__((ext_vector_type(8))) short s16x8;   // 8 bf16 (4 VGPRs)
typedef __attribute__((ext_vector_type(4))) float f32x4;   // MFMA C/D
typedef __attribute__((ext_vector_type(4))) unsigned short u16x4;

__device__ __forceinline__ u16 f2bf(float f) {             // RNE fp32->bf16
    union { float f; unsigned int u; } v; v.f = f;
    v.u += 0x7fff + ((v.u >> 16) & 1);
    return (u16)(v.u >> 16);
}
__device__ __forceinline__ float bf2f(u16 h) {
    union { unsigned int u; float f; } v; v.u = (unsigned)h << 16;
    return v.f;
}
__device__ __forceinline__ void split2(float x, u16& hi, u16& lo) {
    const u16 h = f2bf(x);
    hi = h;
    lo = f2bf(x - bf2f(h));                                // residual ~2^-17 relative
}

// Swizzled LDS tile [64 rows][64 bf16] (128 B rows): byte ^= (row&7)<<4.
__device__ __forceinline__ s16x8 ldf(const u16* buf, int row, int chunk) {
    const int byte = (row * 128 + chunk * 16) ^ ((row & 7) << 4);
    return *(const s16x8*)((const char*)buf + byte);
}
__device__ __forceinline__ void st32(u16* buf, int row, int ch, s16x8 a, s16x8 b) {
    char* p = (char*)buf;
    *(s16x8*)(p + ((row * 128 + ch * 32) ^ ((row & 7) << 4)))      = a;
    *(s16x8*)(p + ((row * 128 + ch * 32 + 16) ^ ((row & 7) << 4))) = b;
}
// attn staging variant (round-4/6/9 validated): chunks ch and ch+4
__device__ __forceinline__ void st_stage(u16* buf, int t, s16x8 v0, s16x8 v1) {
    const int row = t >> 2, ch = t & 3;
    *(s16x8*)((char*)buf + ((row * 128 + ch * 16)       ^ ((row & 7) << 4))) = v0;
    *(s16x8*)((char*)buf + ((row * 128 + (ch + 4) * 16) ^ ((row & 7) << 4))) = v1;
}
__device__ __forceinline__ float hmax4(f32x4 v) {
    return fmaxf(fmaxf(v[0], v[1]), fmaxf(v[2], v[3]));
}
__device__ __forceinline__ float hsum4(f32x4 v) {
    return (v[0] + v[1]) + (v[2] + v[3]);
}

// ---------------------------------------------------------------------------
// Prep: split BOTH weight arrays into hi/lo bf16 in one launch.
// ---------------------------------------------------------------------------
__global__ __launch_bounds__(256)
void split_both(const float* __restrict__ srcA, u16* __restrict__ hiA,
                u16* __restrict__ loA, int n4A,
                const float* __restrict__ srcB, u16* __restrict__ hiB,
                u16* __restrict__ loB, int n4B)
{
    int i = blockIdx.x * 256 + threadIdx.x;
    const float* src; u16 *hi, *lo;
    if (i < n4A) { src = srcA; hi = hiA; lo = loA; }
    else {
        i -= n4A;
        if (i >= n4B) return;
        src = srcB; hi = hiB; lo = loB;
    }
    const float4 v = ((const float4*)src)[i];
    u16 h0,h1,h2,h3,l0,l1,l2,l3;
    split2(v.x,h0,l0); split2(v.y,h1,l1); split2(v.z,h2,l2); split2(v.w,h3,l3);
    u16x4 H = {h0,h1,h2,h3}, L = {l0,l1,l2,l3};
    ((u16x4*)hi)[i] = H;
    ((u16x4*)lo)[i] = L;
}

// ---------------------------------------------------------------------------
// Prep: transpose x [b][c][p] fp32 -> xT hi/lo [b][p][c] bf16 (64x64 tiles)
// ---------------------------------------------------------------------------
__global__ __launch_bounds__(256)
void xpose_x(const float* __restrict__ x, u16* __restrict__ xthi,
             u16* __restrict__ xtlo)
{
    __shared__ float T[64][68];
    const int t  = threadIdx.x;
    const int p0 = blockIdx.x * 64;
    const int c0 = blockIdx.y * 64;
    const int b  = blockIdx.z;
    const int cl = t >> 4, pj = (t & 15) * 4;
    #pragma unroll
    for (int k = 0; k < 4; ++k)
        *(float4*)&T[cl + 16 * k][pj] =
            *(const float4*)&x[((size_t)b * CIN + c0 + cl + 16 * k) * NTOK + p0 + pj];
    __syncthreads();
    const int p = t >> 2, ch = t & 3;
    u16* dhi = xthi + ((size_t)b * NTOK + p0 + p) * CIN + c0 + ch * 16;
    u16* dlo = xtlo + ((size_t)b * NTOK + p0 + p) * CIN + c0 + ch * 16;
    #pragma unroll
    for (int g = 0; g < 2; ++g) {
        s16x8 H, L;
        #pragma unroll
        for (int e = 0; e < 8; ++e) {
            u16 hh, ll;
            split2(T[ch * 16 + g * 8 + e][p], hh, ll);
            H[e] = (short)hh; L[e] = (short)ll;
        }
        *(s16x8*)(dhi + g * 8) = H;
        *(s16x8*)(dlo + g * 8) = L;
    }
}

// ---------------------------------------------------------------------------
// QKV projection, split-bf16 MFMA (round-6/9 validated). Only change:
// Q pre-scale now includes LOG2E so attn softmax runs in exp2 domain.
// ---------------------------------------------------------------------------
__global__ __launch_bounds__(256, 4)
void gemm_qkv_mfma(const u16* __restrict__ Whi, const u16* __restrict__ Wlo,
                   const u16* __restrict__ Xhi, const u16* __restrict__ Xlo,
                   u16* __restrict__ qkt, u16* __restrict__ vd)
{
    __shared__ __align__(16) char smem[32768];
    u16* Ah = (u16*)smem;
    u16* Al = (u16*)(smem + 8192);
    u16* Bh = (u16*)(smem + 16384);
    u16* Bl = (u16*)(smem + 24576);

    const int t = threadIdx.x;
    const int lane = t & 63, w = t >> 6;
    const int lr = lane & 15, lq = lane >> 4;
    const int p0 = blockIdx.x * 64;
    const int m0 = blockIdx.y * 64;
    const int b  = blockIdx.z;
    const int row = t >> 2, ch = t & 3;

    const u16* wh = Whi + (size_t)(m0 + row) * CIN + ch * 16;
    const u16* wl = Wlo + (size_t)(m0 + row) * CIN + ch * 16;
    const u16* xh = Xhi + ((size_t)b * NTOK + p0 + row) * CIN + ch * 16;
    const u16* xl = Xlo + ((size_t)b * NTOK + p0 + row) * CIN + ch * 16;

    f32x4 acc[4] = {};
    for (int kc = 0; kc < CIN; kc += 64) {
        __syncthreads();
        st32(Ah, row, ch, *(const s16x8*)(wh + kc), *(const s16x8*)(wh + kc + 8));
        st32(Al, row, ch, *(const s16x8*)(wl + kc), *(const s16x8*)(wl + kc + 8));
        st32(Bh, row, ch, *(const s16x8*)(xh + kc), *(const s16x8*)(xh + kc + 8));
        st32(Bl, row, ch, *(const s16x8*)(xl + kc), *(const s16x8*)(xl + kc + 8));
        __syncthreads();
        #pragma unroll
        for (int ks = 0; ks < 2; ++ks) {
            const s16x8 ah = ldf(Ah, w * 16 + lr, ks * 4 + lq);
            const s16x8 al = ldf(Al, w * 16 + lr, ks * 4 + lq);
            #pragma unroll
            for (int js = 0; js < 4; ++js) {
                const s16x8 bh = ldf(Bh, js * 16 + lr, ks * 4 + lq);
                const s16x8 bl = ldf(Bl, js * 16 + lr, ks * 4 + lq);
                acc[js] = __builtin_amdgcn_mfma_f32_16x16x32_bf16(ah, bh, acc[js], 0, 0, 0);
                acc[js] = __builtin_amdgcn_mfma_f32_16x16x32_bf16(al, bh, acc[js], 0, 0, 0);
                acc[js] = __builtin_amdgcn_mfma_f32_16x16x32_bf16(ah, bl, acc[js], 0, 0, 0);
            }
        }
    }

    __syncthreads();
    u16* T = Ah;
    char* Tc = (char*)T;
    if (m0 < 1024) {
        const float scale = (m0 < 512) ? ATT_SCALE * LOG2E : 1.0f;  // exp2 domain
        #pragma unroll
        for (int js = 0; js < 4; ++js) {
            const int p = js * 16 + lr;
            #pragma unroll
            for (int r = 0; r < 4; ++r) {
                const int o = w * 16 + lq * 4 + r;
                *(u16*)(Tc + ((p * 128 + o * 2) ^ ((p & 7) << 4))) = f2bf(acc[js][r] * scale);
            }
        }
        __syncthreads();
        const int sidx = (m0 < 512) ? 0 : 1;
        const int h = (m0 & 511) >> 6;
        u16* dst = qkt + ((((size_t)b * 2 + sidx) * NH + h) * NTOK + p0 + row) * 64 + ch * 16;
        *(s16x8*)dst       = *(const s16x8*)(Tc + ((row * 128 + ch * 32)      ^ ((row & 7) << 4)));
        *(s16x8*)(dst + 8) = *(const s16x8*)(Tc + ((row * 128 + ch * 32 + 16) ^ ((row & 7) << 4)));
    } else {
        const int h = (m0 - 1024) >> 6;
        #pragma unroll
        for (int js = 0; js < 4; ++js) {
            const int p = js * 16 + lr;
            #pragma unroll
            for (int r = 0; r < 4; ++r) {
                const int o = w * 16 + lq * 4 + r;
                *(u16*)(Tc + ((o * 128 + p * 2) ^ ((o & 7) << 4))) = f2bf(acc[js][r]);
            }
        }
        __syncthreads();
        u16* dst = vd + (((size_t)b * NH + h) * 64 + row) * NTOK + p0 + ch * 16;
        *(s16x8*)dst       = *(const s16x8*)(Tc + ((row * 128 + ch * 32)      ^ ((row & 7) << 4)));
        *(s16x8*)(dst + 8) = *(const s16x8*)(Tc + ((row * 128 + ch * 32 + 16) ^ ((row & 7) << 4)));
    }
}

// ---------------------------------------------------------------------------
// Flash attention, bf16 MFMA, swapped-QK^T softmax (round-9 validated core),
// now KVBLK=128: two 64-j sub-tiles per barrier pair (double-buffered K/V),
// softmax in exp2 domain (Q carries log2e).
// ---------------------------------------------------------------------------
__global__ __launch_bounds__(256, 3)
void attn_kernel(const u16* __restrict__ qkt, const u16* __restrict__ vd,
                 float* __restrict__ attn_out)
{
    __shared__ __align__(16) u16 Qt[64 * 64];
    __shared__ __align__(16) u16 Kt0[64 * 64];
    __shared__ __align__(16) u16 Vt0[64 * 64];
    __shared__ __align__(16) u16 Kt1[64 * 64];
    __shared__ __align__(16) u16 Vt1[64 * 64];
    __shared__ __align__(16) u16 Ps[64 * 64];

    const int t    = threadIdx.x;
    const int lane = t & 63;
    const int w    = t >> 6;
    const int lr   = lane & 15;
    const int lq   = lane >> 4;

    const int bid     = blockIdx.x;
    const int logical = (bid & 7) * 128 + (bid >> 3);
    const int it = logical & 15;
    const int h  = (logical >> 4) & 7;
    const int b  = logical >> 7;
    const int i0 = it * 64;

    const int srow = t >> 2, sch = t & 3;
    const u16* qg = qkt + ((((size_t)b * 2 + 0) * NH + h) * NTOK + i0 + srow) * 64 + sch * 8;
    const u16* kg = qkt + ((((size_t)b * 2 + 1) * NH + h) * NTOK + srow) * 64 + sch * 8;
    const u16* vg = vd  + (((size_t)b * NH + h) * 64 + srow) * NTOK + sch * 8;

    st_stage(Qt, t, *(const s16x8*)qg, *(const s16x8*)(qg + 32));

    // prefetch j-tiles 0 and 1
    s16x8 ka0 = *(const s16x8*)kg,          ka1 = *(const s16x8*)(kg + 32);
    s16x8 kb0 = *(const s16x8*)(kg + 4096), kb1 = *(const s16x8*)(kg + 4096 + 32);
    s16x8 va0 = *(const s16x8*)vg,          va1 = *(const s16x8*)(vg + 32);
    s16x8 vb0 = *(const s16x8*)(vg + 64),   vb1 = *(const s16x8*)(vg + 64 + 32);

    f32x4 o0 = {0.f,0.f,0.f,0.f}, o1 = o0, o2 = o0, o3 = o0;
    float m_run = -INFINITY, l_run = 0.0f;

    const int ii = w * 16 + lr;            // this lane's query row
    char* pr = (char*)Ps;

    auto process_tile = [&](const u16* Kt, const u16* Vt) {
        // ---- S^T: A = K rows j, B = Q rows i (S already in log2 domain) ----
        f32x4 s0 = {0.f,0.f,0.f,0.f}, s1 = s0, s2 = s0, s3 = s0;
        #pragma unroll
        for (int ks = 0; ks < 2; ++ks) {
            const s16x8 qb = ldf(Qt, w * 16 + lr, ks * 4 + lq);
            s0 = __builtin_amdgcn_mfma_f32_16x16x32_bf16(ldf(Kt,      lr, ks*4+lq), qb, s0, 0,0,0);
            s1 = __builtin_amdgcn_mfma_f32_16x16x32_bf16(ldf(Kt, 16 + lr, ks*4+lq), qb, s1, 0,0,0);
            s2 = __builtin_amdgcn_mfma_f32_16x16x32_bf16(ldf(Kt, 32 + lr, ks*4+lq), qb, s2, 0,0,0);
            s3 = __builtin_amdgcn_mfma_f32_16x16x32_bf16(ldf(Kt, 48 + lr, ks*4+lq), qb, s3, 0,0,0);
        }

        // ---- online softmax (exp2 domain), reduce over lanes {ii, ii+16, ii+32, ii+48} ----
        float mt = fmaxf(fmaxf(hmax4(s0), hmax4(s1)), fmaxf(hmax4(s2), hmax4(s3)));
        mt = fmaxf(mt, __shfl_xor(mt, 16));
        mt = fmaxf(mt, __shfl_xor(mt, 32));
        const float mnew = fmaxf(m_run, mt);
        const float corr = exp2f(m_run - mnew);
        f32x4 p0v, p1v, p2v, p3v;
        #pragma unroll
        for (int r = 0; r < 4; ++r) {
            p0v[r] = exp2f(s0[r] - mnew);
            p1v[r] = exp2f(s1[r] - mnew);
            p2v[r] = exp2f(s2[r] - mnew);
            p3v[r] = exp2f(s3[r] - mnew);
        }
        float lt = (hsum4(p0v) + hsum4(p1v)) + (hsum4(p2v) + hsum4(p3v));
        lt += __shfl_xor(lt, 16);
        lt += __shfl_xor(lt, 32);
        l_run = l_run * corr + lt;
        m_run = mnew;

        // ---- P writes: row ii, cols js*16+lq*4+{0..3}, packed 8B ----
        {
            u16x4 a = { f2bf(p0v[0]), f2bf(p0v[1]), f2bf(p0v[2]), f2bf(p0v[3]) };
            u16x4 bq= { f2bf(p1v[0]), f2bf(p1v[1]), f2bf(p1v[2]), f2bf(p1v[3]) };
            u16x4 c = { f2bf(p2v[0]), f2bf(p2v[1]), f2bf(p2v[2]), f2bf(p2v[3]) };
            u16x4 d = { f2bf(p3v[0]), f2bf(p3v[1]), f2bf(p3v[2]), f2bf(p3v[3]) };
            *(u16x4*)(pr + ((ii * 128 + ( 0 + lq * 4) * 2) ^ ((ii & 7) << 4))) = a;
            *(u16x4*)(pr + ((ii * 128 + (16 + lq * 4) * 2) ^ ((ii & 7) << 4))) = bq;
            *(u16x4*)(pr + ((ii * 128 + (32 + lq * 4) * 2) ^ ((ii & 7) << 4))) = c;
            *(u16x4*)(pr + ((ii * 128 + (48 + lq * 4) * 2) ^ ((ii & 7) << 4))) = d;
        }

        o0 *= corr; o1 *= corr; o2 *= corr; o3 *= corr;

        // ---- PV: O^T[d][i] += V[d][j] * P[i][j] (wave-local Ps rows, in-order) ----
        #pragma unroll
        for (int ks = 0; ks < 2; ++ks) {
            const s16x8 pb = ldf(Ps, w * 16 + lr, ks * 4 + lq);
            o0 = __builtin_amdgcn_mfma_f32_16x16x32_bf16(ldf(Vt,      lr, ks*4+lq), pb, o0, 0,0,0);
            o1 = __builtin_amdgcn_mfma_f32_16x16x32_bf16(ldf(Vt, 16 + lr, ks*4+lq), pb, o1, 0,0,0);
            o2 = __builtin_amdgcn_mfma_f32_16x16x32_bf16(ldf(Vt, 32 + lr, ks*4+lq), pb, o2, 0,0,0);
            o3 = __builtin_amdgcn_mfma_f32_16x16x32_bf16(ldf(Vt, 48 + lr, ks*4+lq), pb, o3, 0,0,0);
        }
    };

    for (int itr = 0; itr < 8; ++itr) {
        __syncthreads();                       // prior iteration's LDS reads done
        st_stage(Kt0, t, ka0, ka1);
        st_stage(Vt0, t, va0, va1);
        st_stage(Kt1, t, kb0, kb1);
        st_stage(Vt1, t, vb0, vb1);
        // prefetch j-tiles 2*itr+2, 2*itr+3 (wrap on last; data unused, L2-hot)
        const int jA = (2 * itr + 2) & 15;
        const int jB = (2 * itr + 3) & 15;
        ka0 = *(const s16x8*)(kg + (size_t)jA * 4096);
        ka1 = *(const s16x8*)(kg + (size_t)jA * 4096 + 32);
        kb0 = *(const s16x8*)(kg + (size_t)jB * 4096);
        kb1 = *(const s16x8*)(kg + (size_t)jB * 4096 + 32);
        va0 = *(const s16x8*)(vg + (size_t)jA * 64);
        va1 = *(const s16x8*)(vg + (size_t)jA * 64 + 32);
        vb0 = *(const s16x8*)(vg + (size_t)jB * 64);
        vb1 = *(const s16x8*)(vg + (size_t)jB * 64 + 32);
        __syncthreads();                       // K/V tiles ready

        process_tile(Kt0, Vt0);
        process_tile(Kt1, Vt1);
    }

    // ---- normalize (lane-local 1/l) and store O^T[d][i] fp32 ----
    const float inv = 1.0f / l_run;
    float* og = attn_out + (((size_t)b * NH + h) * 64) * NTOK + i0 + w * 16 + lr;
    #pragma unroll
    for (int r = 0; r < 4; ++r) {
        og[(size_t)( 0 + lq * 4 + r) * NTOK] = o0[r] * inv;
        og[(size_t)(16 + lq * 4 + r) * NTOK] = o1[r] * inv;
        og[(size_t)(32 + lq * 4 + r) * NTOK] = o2[r] * inv;
        og[(size_t)(48 + lq * 4 + r) * NTOK] = o3[r] * inv;
    }
}

// ---------------------------------------------------------------------------
// Output projection, split-bf16 MFMA (round-9 validated, unchanged).
// ---------------------------------------------------------------------------
__global__ __launch_bounds__(256, 4)
void gemm_out_mfma(const u16* __restrict__ Whi, const u16* __restrict__ Wlo,
                   const float* __restrict__ attn, const float* __restrict__ bias,
                   float* __restrict__ out)
{
    __shared__ __align__(16) char smem[24576];
    u16* Ah = (u16*)smem;
    u16* Al = (u16*)(smem + 8192);
    u16* Bt = (u16*)(smem + 16384);

    const int t = threadIdx.x;
    const int lane = t & 63, w = t >> 6;
    const int lr = lane & 15, lq = lane >> 4;
    const int p0 = blockIdx.x * 64;
    const int m0 = blockIdx.y * 64;
    const int b  = blockIdx.z;
    const int row = t >> 2, ch = t & 3;

    const u16* wh = Whi + (size_t)(m0 + row) * HIDDEN + ch * 16;
    const u16* wl = Wlo + (size_t)(m0 + row) * HIDDEN + ch * 16;
    const float* ab = attn + (size_t)b * HIDDEN * NTOK + p0;
    const int btok = t & 63;          // token row of Bt this thread stages
    const int bog  = (t >> 6) * 16;   // 16 o-columns per wave

    f32x4 acc[4] = {};
    for (int kc = 0; kc < HIDDEN; kc += 64) {
        __syncthreads();
        st32(Ah, row, ch, *(const s16x8*)(wh + kc), *(const s16x8*)(wh + kc + 8));
        st32(Al, row, ch, *(const s16x8*)(wl + kc), *(const s16x8*)(wl + kc + 8));
        {
            s16x8 H0, H1;
            #pragma unroll
            for (int e = 0; e < 8; ++e)
                H0[e] = (short)f2bf(ab[(size_t)(kc + bog + e) * NTOK + btok]);
            #pragma unroll
            for (int e = 0; e < 8; ++e)
                H1[e] = (short)f2bf(ab[(size_t)(kc + bog + 8 + e) * NTOK + btok]);
            char* bp = (char*)Bt;
            *(s16x8*)(bp + ((btok * 128 + bog * 2)      ^ ((btok & 7) << 4))) = H0;
            *(s16x8*)(bp + ((btok * 128 + bog * 2 + 16) ^ ((btok & 7) << 4))) = H1;
        }
        __syncthreads();
        #pragma unroll
        for (int ks = 0; ks < 2; ++ks) {
            const s16x8 ah = ldf(Ah, w * 16 + lr, ks * 4 + lq);
            const s16x8 al = ldf(Al, w * 16 + lr, ks * 4 + lq);
            #pragma unroll
            for (int js = 0; js < 4; ++js) {
                const s16x8 bh = ldf(Bt, js * 16 + lr, ks * 4 + lq);
                acc[js] = __builtin_amdgcn_mfma_f32_16x16x32_bf16(ah, bh, acc[js], 0, 0, 0);
                acc[js] = __builtin_amdgcn_mfma_f32_16x16x32_bf16(al, bh, acc[js], 0, 0, 0);
            }
        }
    }

    __syncthreads();
    float* T = (float*)smem;              // 64*68*4 = 17408 B < 24576
    #pragma unroll
    for (int js = 0; js < 4; ++js) {
        const int p = js * 16 + lr;
        #pragma unroll
        for (int r = 0; r < 4; ++r)
            T[(w * 16 + lq * 4 + r) * 68 + p] = acc[js][r];
    }
    __syncthreads();
    const float bv = bias[m0 + row];
    float* dst = out + ((size_t)b * CIN + m0 + row) * NTOK + p0;
    #pragma unroll
    for (int q = 0; q < 4; ++q) {
        float4 v = *(const float4*)&T[row * 68 + ch * 4 + q * 16];
        v.x += bv; v.y += bv; v.z += bv; v.w += bv;
        *(float4*)&dst[ch * 4 + q * 16] = v;
    }
}

// ---------------------------------------------------------------------------
extern "C" void kernel_launch(void* const* d_in, const int* in_sizes, int n_in,
                              void* d_out, int out_size, void* d_ws, size_t ws_size,
                              hipStream_t stream)
{
    const float* x    = (const float*)d_in[0];   // [8][256][1024]
    const float* Wqkv = (const float*)d_in[1];   // [1536][256]
    const float* Wout = (const float*)d_in[2];   // [256][512]
    const float* bout = (const float*)d_in[3];   // [256]
    float* out = (float*)d_out;                  // [8][256][1024]

    char* ws = (char*)d_ws;
    u16* Wqhi = (u16*)ws;                         ws += (size_t)O3 * CIN * 2;
    u16* Wqlo = (u16*)ws;                         ws += (size_t)O3 * CIN * 2;
    u16* Wohi = (u16*)ws;                         ws += (size_t)CIN * HIDDEN * 2;
    u16* Wolo = (u16*)ws;                         ws += (size_t)CIN * HIDDEN * 2;
    u16* xThi = (u16*)ws;                         ws += (size_t)BATCH * NTOK * CIN * 2;
    u16* xTlo = (u16*)ws;                         ws += (size_t)BATCH * NTOK * CIN * 2;
    u16* qkt  = (u16*)ws;                         ws += (size_t)BATCH * 2 * NH * NTOK * HD * 2;
    u16* vd   = (u16*)ws;                         ws += (size_t)BATCH * NH * HD * NTOK * 2;
    float* attn = (float*)ws;                     ws += (size_t)BATCH * HIDDEN * NTOK * 4;

    const int n4A = O3 * CIN / 4, n4B = CIN * HIDDEN / 4;
    split_both<<<dim3((n4A + n4B + 255) / 256), 256, 0, stream>>>(
        Wqkv, Wqhi, Wqlo, n4A, Wout, Wohi, Wolo, n4B);
    xpose_x<<<dim3(16, 4, BATCH), 256, 0, stream>>>(x, xThi, xTlo);

    gemm_qkv_mfma<<<dim3(16, 24, BATCH), 256, 0, stream>>>(Wqhi, Wqlo, xThi, xTlo, qkt, vd);
    attn_kernel<<<dim3(1024), 256, 0, stream>>>(qkt, vd, attn);
    gemm_out_mfma<<<dim3(16, 4, BATCH), 256, 0, stream>>>(Wohi, Wolo, attn, bout, out);
}

// Round 11
// 144.371 us; speedup vs baseline: 1.0780x; 1.0780x over previous
//
#include <hip/hip_runtime.h>
#include <math.h>

#define NH 8
#define HD 64
#define NTOK 1024
#define CIN 256
#define HIDDEN 512
#define O3 1536
#define BATCH 8
#define ATT_SCALE 0.125f
#define LOG2E 1.44269504f

typedef unsigned short u16;
typedef __attribute__((ext_vector_type(8))) short s16x8;   // 8 bf16 (4 VGPRs)
typedef __attribute__((ext_vector_type(4))) float f32x4;   // MFMA C/D
typedef __attribute__((ext_vector_type(4))) unsigned short u16x4;

__device__ __forceinline__ u16 f2bf(float f) {             // RNE fp32->bf16
    union { float f; unsigned int u; } v; v.f = f;
    v.u += 0x7fff + ((v.u >> 16) & 1);
    return (u16)(v.u >> 16);
}
__device__ __forceinline__ float bf2f(u16 h) {
    union { unsigned int u; float f; } v; v.u = (unsigned)h << 16;
    return v.f;
}
__device__ __forceinline__ void split2(float x, u16& hi, u16& lo) {
    const u16 h = f2bf(x);
    hi = h;
    lo = f2bf(x - bf2f(h));                                // residual ~2^-17 relative
}

// Swizzled LDS tile [64 rows][64 bf16] (128 B rows): byte ^= (row&7)<<4.
__device__ __forceinline__ s16x8 ldf(const u16* buf, int row, int chunk) {
    const int byte = (row * 128 + chunk * 16) ^ ((row & 7) << 4);
    return *(const s16x8*)((const char*)buf + byte);
}
__device__ __forceinline__ void st32(u16* buf, int row, int ch, s16x8 a, s16x8 b) {
    char* p = (char*)buf;
    *(s16x8*)(p + ((row * 128 + ch * 32) ^ ((row & 7) << 4)))      = a;
    *(s16x8*)(p + ((row * 128 + ch * 32 + 16) ^ ((row & 7) << 4))) = b;
}
// attn staging variant (round-4/6/9 validated): chunks ch and ch+4
__device__ __forceinline__ void st_stage(u16* buf, int t, s16x8 v0, s16x8 v1) {
    const int row = t >> 2, ch = t & 3;
    *(s16x8*)((char*)buf + ((row * 128 + ch * 16)       ^ ((row & 7) << 4))) = v0;
    *(s16x8*)((char*)buf + ((row * 128 + (ch + 4) * 16) ^ ((row & 7) << 4))) = v1;
}
__device__ __forceinline__ float hmax4(f32x4 v) {
    return fmaxf(fmaxf(v[0], v[1]), fmaxf(v[2], v[3]));
}
__device__ __forceinline__ float hsum4(f32x4 v) {
    return (v[0] + v[1]) + (v[2] + v[3]);
}

// ---------------------------------------------------------------------------
// Prep: split BOTH weight arrays into hi/lo bf16 in one launch.
// ---------------------------------------------------------------------------
__global__ __launch_bounds__(256)
void split_both(const float* __restrict__ srcA, u16* __restrict__ hiA,
                u16* __restrict__ loA, int n4A,
                const float* __restrict__ srcB, u16* __restrict__ hiB,
                u16* __restrict__ loB, int n4B)
{
    int i = blockIdx.x * 256 + threadIdx.x;
    const float* src; u16 *hi, *lo;
    if (i < n4A) { src = srcA; hi = hiA; lo = loA; }
    else {
        i -= n4A;
        if (i >= n4B) return;
        src = srcB; hi = hiB; lo = loB;
    }
    const float4 v = ((const float4*)src)[i];
    u16 h0,h1,h2,h3,l0,l1,l2,l3;
    split2(v.x,h0,l0); split2(v.y,h1,l1); split2(v.z,h2,l2); split2(v.w,h3,l3);
    u16x4 H = {h0,h1,h2,h3}, L = {l0,l1,l2,l3};
    ((u16x4*)hi)[i] = H;
    ((u16x4*)lo)[i] = L;
}

// ---------------------------------------------------------------------------
// Prep: transpose x [b][c][p] fp32 -> xT hi/lo [b][p][c] bf16 (64x64 tiles)
// ---------------------------------------------------------------------------
__global__ __launch_bounds__(256)
void xpose_x(const float* __restrict__ x, u16* __restrict__ xthi,
             u16* __restrict__ xtlo)
{
    __shared__ float T[64][68];
    const int t  = threadIdx.x;
    const int p0 = blockIdx.x * 64;
    const int c0 = blockIdx.y * 64;
    const int b  = blockIdx.z;
    const int cl = t >> 4, pj = (t & 15) * 4;
    #pragma unroll
    for (int k = 0; k < 4; ++k)
        *(float4*)&T[cl + 16 * k][pj] =
            *(const float4*)&x[((size_t)b * CIN + c0 + cl + 16 * k) * NTOK + p0 + pj];
    __syncthreads();
    const int p = t >> 2, ch = t & 3;
    u16* dhi = xthi + ((size_t)b * NTOK + p0 + p) * CIN + c0 + ch * 16;
    u16* dlo = xtlo + ((size_t)b * NTOK + p0 + p) * CIN + c0 + ch * 16;
    #pragma unroll
    for (int g = 0; g < 2; ++g) {
        s16x8 H, L;
        #pragma unroll
        for (int e = 0; e < 8; ++e) {
            u16 hh, ll;
            split2(T[ch * 16 + g * 8 + e][p], hh, ll);
            H[e] = (short)hh; L[e] = (short)ll;
        }
        *(s16x8*)(dhi + g * 8) = H;
        *(s16x8*)(dlo + g * 8) = L;
    }
}

// ---------------------------------------------------------------------------
// QKV projection, split-bf16 MFMA (round-6/9/10 validated).
// Q pre-scale includes LOG2E (attn softmax runs in exp2 domain).
// ---------------------------------------------------------------------------
__global__ __launch_bounds__(256, 4)
void gemm_qkv_mfma(const u16* __restrict__ Whi, const u16* __restrict__ Wlo,
                   const u16* __restrict__ Xhi, const u16* __restrict__ Xlo,
                   u16* __restrict__ qkt, u16* __restrict__ vd)
{
    __shared__ __align__(16) char smem[32768];
    u16* Ah = (u16*)smem;
    u16* Al = (u16*)(smem + 8192);
    u16* Bh = (u16*)(smem + 16384);
    u16* Bl = (u16*)(smem + 24576);

    const int t = threadIdx.x;
    const int lane = t & 63, w = t >> 6;
    const int lr = lane & 15, lq = lane >> 4;
    const int p0 = blockIdx.x * 64;
    const int m0 = blockIdx.y * 64;
    const int b  = blockIdx.z;
    const int row = t >> 2, ch = t & 3;

    const u16* wh = Whi + (size_t)(m0 + row) * CIN + ch * 16;
    const u16* wl = Wlo + (size_t)(m0 + row) * CIN + ch * 16;
    const u16* xh = Xhi + ((size_t)b * NTOK + p0 + row) * CIN + ch * 16;
    const u16* xl = Xlo + ((size_t)b * NTOK + p0 + row) * CIN + ch * 16;

    f32x4 acc[4] = {};
    for (int kc = 0; kc < CIN; kc += 64) {
        __syncthreads();
        st32(Ah, row, ch, *(const s16x8*)(wh + kc), *(const s16x8*)(wh + kc + 8));
        st32(Al, row, ch, *(const s16x8*)(wl + kc), *(const s16x8*)(wl + kc + 8));
        st32(Bh, row, ch, *(const s16x8*)(xh + kc), *(const s16x8*)(xh + kc + 8));
        st32(Bl, row, ch, *(const s16x8*)(xl + kc), *(const s16x8*)(xl + kc + 8));
        __syncthreads();
        #pragma unroll
        for (int ks = 0; ks < 2; ++ks) {
            const s16x8 ah = ldf(Ah, w * 16 + lr, ks * 4 + lq);
            const s16x8 al = ldf(Al, w * 16 + lr, ks * 4 + lq);
            #pragma unroll
            for (int js = 0; js < 4; ++js) {
                const s16x8 bh = ldf(Bh, js * 16 + lr, ks * 4 + lq);
                const s16x8 bl = ldf(Bl, js * 16 + lr, ks * 4 + lq);
                acc[js] = __builtin_amdgcn_mfma_f32_16x16x32_bf16(ah, bh, acc[js], 0, 0, 0);
                acc[js] = __builtin_amdgcn_mfma_f32_16x16x32_bf16(al, bh, acc[js], 0, 0, 0);
                acc[js] = __builtin_amdgcn_mfma_f32_16x16x32_bf16(ah, bl, acc[js], 0, 0, 0);
            }
        }
    }

    __syncthreads();
    u16* T = Ah;
    char* Tc = (char*)T;
    if (m0 < 1024) {
        const float scale = (m0 < 512) ? ATT_SCALE * LOG2E : 1.0f;  // exp2 domain
        #pragma unroll
        for (int js = 0; js < 4; ++js) {
            const int p = js * 16 + lr;
            #pragma unroll
            for (int r = 0; r < 4; ++r) {
                const int o = w * 16 + lq * 4 + r;
                *(u16*)(Tc + ((p * 128 + o * 2) ^ ((p & 7) << 4))) = f2bf(acc[js][r] * scale);
            }
        }
        __syncthreads();
        const int sidx = (m0 < 512) ? 0 : 1;
        const int h = (m0 & 511) >> 6;
        u16* dst = qkt + ((((size_t)b * 2 + sidx) * NH + h) * NTOK + p0 + row) * 64 + ch * 16;
        *(s16x8*)dst       = *(const s16x8*)(Tc + ((row * 128 + ch * 32)      ^ ((row & 7) << 4)));
        *(s16x8*)(dst + 8) = *(const s16x8*)(Tc + ((row * 128 + ch * 32 + 16) ^ ((row & 7) << 4)));
    } else {
        const int h = (m0 - 1024) >> 6;
        #pragma unroll
        for (int js = 0; js < 4; ++js) {
            const int p = js * 16 + lr;
            #pragma unroll
            for (int r = 0; r < 4; ++r) {
                const int o = w * 16 + lq * 4 + r;
                *(u16*)(Tc + ((o * 128 + p * 2) ^ ((o & 7) << 4))) = f2bf(acc[js][r]);
            }
        }
        __syncthreads();
        u16* dst = vd + (((size_t)b * NH + h) * 64 + row) * NTOK + p0 + ch * 16;
        *(s16x8*)dst       = *(const s16x8*)(Tc + ((row * 128 + ch * 32)      ^ ((row & 7) << 4)));
        *(s16x8*)(dst + 8) = *(const s16x8*)(Tc + ((row * 128 + ch * 32 + 16) ^ ((row & 7) << 4)));
    }
}

// ---------------------------------------------------------------------------
// Flash attention — round-9 structure (KVBLK=64, 32KB LDS, 4 blocks/CU),
// + Q-fragment hoist (constant across tiles), + defer-max (T13, THR=8 in
// log2 domain), exp2-domain softmax.
// ---------------------------------------------------------------------------
__global__ __launch_bounds__(256, 4)
void attn_kernel(const u16* __restrict__ qkt, const u16* __restrict__ vd,
                 float* __restrict__ attn_out)
{
    __shared__ __align__(16) u16 Qt[64 * 64];
    __shared__ __align__(16) u16 Kt[64 * 64];
    __shared__ __align__(16) u16 Vt[64 * 64];
    __shared__ __align__(16) u16 Ps[64 * 64];

    const int t    = threadIdx.x;
    const int lane = t & 63;
    const int w    = t >> 6;
    const int lr   = lane & 15;
    const int lq   = lane >> 4;

    const int bid     = blockIdx.x;
    const int logical = (bid & 7) * 128 + (bid >> 3);
    const int it = logical & 15;
    const int h  = (logical >> 4) & 7;
    const int b  = logical >> 7;
    const int i0 = it * 64;

    const int srow = t >> 2, sch = t & 3;
    const u16* qg = qkt + ((((size_t)b * 2 + 0) * NH + h) * NTOK + i0 + srow) * 64 + sch * 8;
    const u16* kg = qkt + ((((size_t)b * 2 + 1) * NH + h) * NTOK + srow) * 64 + sch * 8;
    const u16* vg = vd  + (((size_t)b * NH + h) * 64 + srow) * NTOK + sch * 8;

    st_stage(Qt, t, *(const s16x8*)qg, *(const s16x8*)(qg + 32));

    s16x8 k0 = *(const s16x8*)kg, k1 = *(const s16x8*)(kg + 32);
    s16x8 v0 = *(const s16x8*)vg, v1 = *(const s16x8*)(vg + 32);

    // ---- Q-fragment hoist: constant across all 16 j-tiles ----
    __syncthreads();
    const s16x8 qb0 = ldf(Qt, w * 16 + lr, lq);
    const s16x8 qb1 = ldf(Qt, w * 16 + lr, 4 + lq);

    f32x4 o0 = {0.f,0.f,0.f,0.f}, o1 = o0, o2 = o0, o3 = o0;
    float m_run = -INFINITY, l_run = 0.0f;

    const int ii = w * 16 + lr;            // this lane's query row
    char* pr = (char*)Ps;

    for (int jt = 0; jt < 16; ++jt) {
        __syncthreads();                       // prior tile's LDS reads done
        st_stage(Kt, t, k0, k1);
        st_stage(Vt, t, v0, v1);
        const int jn = (jt + 1) & 15;          // prefetch next tile (wraps; L2-hot)
        k0 = *(const s16x8*)(kg + (size_t)jn * 4096);
        k1 = *(const s16x8*)(kg + (size_t)jn * 4096 + 32);
        v0 = *(const s16x8*)(vg + (size_t)jn * 64);
        v1 = *(const s16x8*)(vg + (size_t)jn * 64 + 32);
        __syncthreads();                       // K/V tiles ready

        // ---- S^T tile: A = K rows j, B = Q rows i (log2 domain) ----
        f32x4 s0 = {0.f,0.f,0.f,0.f}, s1 = s0, s2 = s0, s3 = s0;
        s0 = __builtin_amdgcn_mfma_f32_16x16x32_bf16(ldf(Kt,      lr, lq), qb0, s0, 0,0,0);
        s1 = __builtin_amdgcn_mfma_f32_16x16x32_bf16(ldf(Kt, 16 + lr, lq), qb0, s1, 0,0,0);
        s2 = __builtin_amdgcn_mfma_f32_16x16x32_bf16(ldf(Kt, 32 + lr, lq), qb0, s2, 0,0,0);
        s3 = __builtin_amdgcn_mfma_f32_16x16x32_bf16(ldf(Kt, 48 + lr, lq), qb0, s3, 0,0,0);
        s0 = __builtin_amdgcn_mfma_f32_16x16x32_bf16(ldf(Kt,      lr, 4 + lq), qb1, s0, 0,0,0);
        s1 = __builtin_amdgcn_mfma_f32_16x16x32_bf16(ldf(Kt, 16 + lr, 4 + lq), qb1, s1, 0,0,0);
        s2 = __builtin_amdgcn_mfma_f32_16x16x32_bf16(ldf(Kt, 32 + lr, 4 + lq), qb1, s2, 0,0,0);
        s3 = __builtin_amdgcn_mfma_f32_16x16x32_bf16(ldf(Kt, 48 + lr, 4 + lq), qb1, s3, 0,0,0);

        // ---- online softmax, defer-max: rescale only when max grew > 8 ----
        float mt = fmaxf(fmaxf(hmax4(s0), hmax4(s1)), fmaxf(hmax4(s2), hmax4(s3)));
        mt = fmaxf(mt, __shfl_xor(mt, 16));
        mt = fmaxf(mt, __shfl_xor(mt, 32));
        if (!__all(mt - m_run <= 8.0f)) {
            const float mnew = fmaxf(m_run, mt);
            const float corr = exp2f(m_run - mnew);
            l_run *= corr;
            o0 *= corr; o1 *= corr; o2 *= corr; o3 *= corr;
            m_run = mnew;
        }
        f32x4 p0v, p1v, p2v, p3v;
        #pragma unroll
        for (int r = 0; r < 4; ++r) {
            p0v[r] = exp2f(s0[r] - m_run);
            p1v[r] = exp2f(s1[r] - m_run);
            p2v[r] = exp2f(s2[r] - m_run);
            p3v[r] = exp2f(s3[r] - m_run);
        }
        float lt = (hsum4(p0v) + hsum4(p1v)) + (hsum4(p2v) + hsum4(p3v));
        lt += __shfl_xor(lt, 16);
        lt += __shfl_xor(lt, 32);
        l_run += lt;

        // ---- P writes: row ii, cols js*16+lq*4+{0..3}, packed 8B ----
        {
            u16x4 a = { f2bf(p0v[0]), f2bf(p0v[1]), f2bf(p0v[2]), f2bf(p0v[3]) };
            u16x4 bq= { f2bf(p1v[0]), f2bf(p1v[1]), f2bf(p1v[2]), f2bf(p1v[3]) };
            u16x4 c = { f2bf(p2v[0]), f2bf(p2v[1]), f2bf(p2v[2]), f2bf(p2v[3]) };
            u16x4 d = { f2bf(p3v[0]), f2bf(p3v[1]), f2bf(p3v[2]), f2bf(p3v[3]) };
            *(u16x4*)(pr + ((ii * 128 + ( 0 + lq * 4) * 2) ^ ((ii & 7) << 4))) = a;
            *(u16x4*)(pr + ((ii * 128 + (16 + lq * 4) * 2) ^ ((ii & 7) << 4))) = bq;
            *(u16x4*)(pr + ((ii * 128 + (32 + lq * 4) * 2) ^ ((ii & 7) << 4))) = c;
            *(u16x4*)(pr + ((ii * 128 + (48 + lq * 4) * 2) ^ ((ii & 7) << 4))) = d;
        }

        // ---- PV: O^T[d][i] += V[d][j] * P[i][j] (wave-local Ps rows) ----
        #pragma unroll
        for (int ks = 0; ks < 2; ++ks) {
            const s16x8 pb = ldf(Ps, w * 16 + lr, ks * 4 + lq);
            o0 = __builtin_amdgcn_mfma_f32_16x16x32_bf16(ldf(Vt,      lr, ks*4+lq), pb, o0, 0,0,0);
            o1 = __builtin_amdgcn_mfma_f32_16x16x32_bf16(ldf(Vt, 16 + lr, ks*4+lq), pb, o1, 0,0,0);
            o2 = __builtin_amdgcn_mfma_f32_16x16x32_bf16(ldf(Vt, 32 + lr, ks*4+lq), pb, o2, 0,0,0);
            o3 = __builtin_amdgcn_mfma_f32_16x16x32_bf16(ldf(Vt, 48 + lr, ks*4+lq), pb, o3, 0,0,0);
        }
    }

    // ---- normalize (lane-local 1/l) and store O^T[d][i] fp32 ----
    const float inv = 1.0f / l_run;
    float* og = attn_out + (((size_t)b * NH + h) * 64) * NTOK + i0 + w * 16 + lr;
    #pragma unroll
    for (int r = 0; r < 4; ++r) {
        og[(size_t)( 0 + lq * 4 + r) * NTOK] = o0[r] * inv;
        og[(size_t)(16 + lq * 4 + r) * NTOK] = o1[r] * inv;
        og[(size_t)(32 + lq * 4 + r) * NTOK] = o2[r] * inv;
        og[(size_t)(48 + lq * 4 + r) * NTOK] = o3[r] * inv;
    }
}

// ---------------------------------------------------------------------------
// Output projection, split-bf16 MFMA (round-9/10 validated, unchanged).
// ---------------------------------------------------------------------------
__global__ __launch_bounds__(256, 4)
void gemm_out_mfma(const u16* __restrict__ Whi, const u16* __restrict__ Wlo,
                   const float* __restrict__ attn, const float* __restrict__ bias,
                   float* __restrict__ out)
{
    __shared__ __align__(16) char smem[24576];
    u16* Ah = (u16*)smem;
    u16* Al = (u16*)(smem + 8192);
    u16* Bt = (u16*)(smem + 16384);

    const int t = threadIdx.x;
    const int lane = t & 63, w = t >> 6;
    const int lr = lane & 15, lq = lane >> 4;
    const int p0 = blockIdx.x * 64;
    const int m0 = blockIdx.y * 64;
    const int b  = blockIdx.z;
    const int row = t >> 2, ch = t & 3;

    const u16* wh = Whi + (size_t)(m0 + row) * HIDDEN + ch * 16;
    const u16* wl = Wlo + (size_t)(m0 + row) * HIDDEN + ch * 16;
    const float* ab = attn + (size_t)b * HIDDEN * NTOK + p0;
    const int btok = t & 63;          // token row of Bt this thread stages
    const int bog  = (t >> 6) * 16;   // 16 o-columns per wave

    f32x4 acc[4] = {};
    for (int kc = 0; kc < HIDDEN; kc += 64) {
        __syncthreads();
        st32(Ah, row, ch, *(const s16x8*)(wh + kc), *(const s16x8*)(wh + kc + 8));
        st32(Al, row, ch, *(const s16x8*)(wl + kc), *(const s16x8*)(wl + kc + 8));
        {
            s16x8 H0, H1;
            #pragma unroll
            for (int e = 0; e < 8; ++e)
                H0[e] = (short)f2bf(ab[(size_t)(kc + bog + e) * NTOK + btok]);
            #pragma unroll
            for (int e = 0; e < 8; ++e)
                H1[e] = (short)f2bf(ab[(size_t)(kc + bog + 8 + e) * NTOK + btok]);
            char* bp = (char*)Bt;
            *(s16x8*)(bp + ((btok * 128 + bog * 2)      ^ ((btok & 7) << 4))) = H0;
            *(s16x8*)(bp + ((btok * 128 + bog * 2 + 16) ^ ((btok & 7) << 4))) = H1;
        }
        __syncthreads();
        #pragma unroll
        for (int ks = 0; ks < 2; ++ks) {
            const s16x8 ah = ldf(Ah, w * 16 + lr, ks * 4 + lq);
            const s16x8 al = ldf(Al, w * 16 + lr, ks * 4 + lq);
            #pragma unroll
            for (int js = 0; js < 4; ++js) {
                const s16x8 bh = ldf(Bt, js * 16 + lr, ks * 4 + lq);
                acc[js] = __builtin_amdgcn_mfma_f32_16x16x32_bf16(ah, bh, acc[js], 0, 0, 0);
                acc[js] = __builtin_amdgcn_mfma_f32_16x16x32_bf16(al, bh, acc[js], 0, 0, 0);
            }
        }
    }

    __syncthreads();
    float* T = (float*)smem;              // 64*68*4 = 17408 B < 24576
    #pragma unroll
    for (int js = 0; js < 4; ++js) {
        const int p = js * 16 + lr;
        #pragma unroll
        for (int r = 0; r < 4; ++r)
            T[(w * 16 + lq * 4 + r) * 68 + p] = acc[js][r];
    }
    __syncthreads();
    const float bv = bias[m0 + row];
    float* dst = out + ((size_t)b * CIN + m0 + row) * NTOK + p0;
    #pragma unroll
    for (int q = 0; q < 4; ++q) {
        float4 v = *(const float4*)&T[row * 68 + ch * 4 + q * 16];
        v.x += bv; v.y += bv; v.z += bv; v.w += bv;
        *(float4*)&dst[ch * 4 + q * 16] = v;
    }
}

// ---------------------------------------------------------------------------
extern "C" void kernel_launch(void* const* d_in, const int* in_sizes, int n_in,
                              void* d_out, int out_size, void* d_ws, size_t ws_size,
                              hipStream_t stream)
{
    const float* x    = (const float*)d_in[0];   // [8][256][1024]
    const float* Wqkv = (const float*)d_in[1];   // [1536][256]
    const float* Wout = (const float*)d_in[2];   // [256][512]
    const float* bout = (const float*)d_in[3];   // [256]
    float* out = (float*)d_out;                  // [8][256][1024]

    char* ws = (char*)d_ws;
    u16* Wqhi = (u16*)ws;                         ws += (size_t)O3 * CIN * 2;
    u16* Wqlo = (u16*)ws;                         ws += (size_t)O3 * CIN * 2;
    u16* Wohi = (u16*)ws;                         ws += (size_t)CIN * HIDDEN * 2;
    u16* Wolo = (u16*)ws;                         ws += (size_t)CIN * HIDDEN * 2;
    u16* xThi = (u16*)ws;                         ws += (size_t)BATCH * NTOK * CIN * 2;
    u16* xTlo = (u16*)ws;                         ws += (size_t)BATCH * NTOK * CIN * 2;
    u16* qkt  = (u16*)ws;                         ws += (size_t)BATCH * 2 * NH * NTOK * HD * 2;
    u16* vd   = (u16*)ws;                         ws += (size_t)BATCH * NH * HD * NTOK * 2;
    float* attn = (float*)ws;                     ws += (size_t)BATCH * HIDDEN * NTOK * 4;

    const int n4A = O3 * CIN / 4, n4B = CIN * HIDDEN / 4;
    split_both<<<dim3((n4A + n4B + 255) / 256), 256, 0, stream>>>(
        Wqkv, Wqhi, Wqlo, n4A, Wout, Wohi, Wolo, n4B);
    xpose_x<<<dim3(16, 4, BATCH), 256, 0, stream>>>(x, xThi, xTlo);

    gemm_qkv_mfma<<<dim3(16, 24, BATCH), 256, 0, stream>>>(Wqhi, Wqlo, xThi, xTlo, qkt, vd);
    attn_kernel<<<dim3(1024), 256, 0, stream>>>(qkt, vd, attn);
    gemm_out_mfma<<<dim3(16, 4, BATCH), 256, 0, stream>>>(Wohi, Wolo, attn, bout, out);
}

// Round 12
// 142.927 us; speedup vs baseline: 1.0888x; 1.0101x over previous
//
#include <hip/hip_runtime.h>
#include <math.h>

#define NH 8
#define HD 64
#define NTOK 1024
#define CIN 256
#define HIDDEN 512
#define O3 1536
#define BATCH 8
#define ATT_SCALE 0.125f
#define LOG2E 1.44269504f

typedef unsigned short u16;
typedef __attribute__((ext_vector_type(8))) short s16x8;   // 8 bf16 (4 VGPRs)
typedef __attribute__((ext_vector_type(4))) float f32x4;   // MFMA C/D
typedef __attribute__((ext_vector_type(4))) unsigned short u16x4;
typedef __attribute__((ext_vector_type(2))) unsigned int u32x2;
typedef __attribute__((ext_vector_type(4))) unsigned int u32x4v;

__device__ __forceinline__ u16 f2bf(float f) {             // RNE fp32->bf16 (scalar)
    union { float f; unsigned int u; } v; v.f = f;
    v.u += 0x7fff + ((v.u >> 16) & 1);
    return (u16)(v.u >> 16);
}
__device__ __forceinline__ float bf2f(u16 h) {
    union { unsigned int u; float f; } v; v.u = (unsigned)h << 16;
    return v.f;
}
// HW packed convert: lo16 = bf16(a), hi16 = bf16(b); RNE — same as f2bf.
__device__ __forceinline__ unsigned cvtpk(float a, float b) {
    unsigned r;
    asm("v_cvt_pk_bf16_f32 %0, %1, %2" : "=v"(r) : "v"(a), "v"(b));
    return r;
}
__device__ __forceinline__ void split2(float x, u16& hi, u16& lo) {
    const u16 h = f2bf(x);
    hi = h;
    lo = f2bf(x - bf2f(h));                                // residual ~2^-17 relative
}

// Swizzled LDS tile [64 rows][64 bf16] (128 B rows): byte ^= (row&7)<<4.
__device__ __forceinline__ s16x8 ldf(const u16* buf, int row, int chunk) {
    const int byte = (row * 128 + chunk * 16) ^ ((row & 7) << 4);
    return *(const s16x8*)((const char*)buf + byte);
}
__device__ __forceinline__ void st32(u16* buf, int row, int ch, s16x8 a, s16x8 b) {
    char* p = (char*)buf;
    *(s16x8*)(p + ((row * 128 + ch * 32) ^ ((row & 7) << 4)))      = a;
    *(s16x8*)(p + ((row * 128 + ch * 32 + 16) ^ ((row & 7) << 4))) = b;
}
// attn staging variant (round-4/6/9 validated): chunks ch and ch+4
__device__ __forceinline__ void st_stage(u16* buf, int t, s16x8 v0, s16x8 v1) {
    const int row = t >> 2, ch = t & 3;
    *(s16x8*)((char*)buf + ((row * 128 + ch * 16)       ^ ((row & 7) << 4))) = v0;
    *(s16x8*)((char*)buf + ((row * 128 + (ch + 4) * 16) ^ ((row & 7) << 4))) = v1;
}
__device__ __forceinline__ float hmax4(f32x4 v) {
    return fmaxf(fmaxf(v[0], v[1]), fmaxf(v[2], v[3]));
}
__device__ __forceinline__ float hsum4(f32x4 v) {
    return (v[0] + v[1]) + (v[2] + v[3]);
}

// ---------------------------------------------------------------------------
// Prep: split BOTH weight arrays into hi/lo bf16 in one launch.
// ---------------------------------------------------------------------------
__global__ __launch_bounds__(256)
void split_both(const float* __restrict__ srcA, u16* __restrict__ hiA,
                u16* __restrict__ loA, int n4A,
                const float* __restrict__ srcB, u16* __restrict__ hiB,
                u16* __restrict__ loB, int n4B)
{
    int i = blockIdx.x * 256 + threadIdx.x;
    const float* src; u16 *hi, *lo;
    if (i < n4A) { src = srcA; hi = hiA; lo = loA; }
    else {
        i -= n4A;
        if (i >= n4B) return;
        src = srcB; hi = hiB; lo = loB;
    }
    const float4 v = ((const float4*)src)[i];
    u16 h0,h1,h2,h3,l0,l1,l2,l3;
    split2(v.x,h0,l0); split2(v.y,h1,l1); split2(v.z,h2,l2); split2(v.w,h3,l3);
    u16x4 H = {h0,h1,h2,h3}, L = {l0,l1,l2,l3};
    ((u16x4*)hi)[i] = H;
    ((u16x4*)lo)[i] = L;
}

// ---------------------------------------------------------------------------
// Prep: transpose x [b][c][p] fp32 -> xT hi/lo [b][p][c] bf16 (64x64 tiles)
// ---------------------------------------------------------------------------
__global__ __launch_bounds__(256)
void xpose_x(const float* __restrict__ x, u16* __restrict__ xthi,
             u16* __restrict__ xtlo)
{
    __shared__ float T[64][68];
    const int t  = threadIdx.x;
    const int p0 = blockIdx.x * 64;
    const int c0 = blockIdx.y * 64;
    const int b  = blockIdx.z;
    const int cl = t >> 4, pj = (t & 15) * 4;
    #pragma unroll
    for (int k = 0; k < 4; ++k)
        *(float4*)&T[cl + 16 * k][pj] =
            *(const float4*)&x[((size_t)b * CIN + c0 + cl + 16 * k) * NTOK + p0 + pj];
    __syncthreads();
    const int p = t >> 2, ch = t & 3;
    u16* dhi = xthi + ((size_t)b * NTOK + p0 + p) * CIN + c0 + ch * 16;
    u16* dlo = xtlo + ((size_t)b * NTOK + p0 + p) * CIN + c0 + ch * 16;
    #pragma unroll
    for (int g = 0; g < 2; ++g) {
        s16x8 H, L;
        #pragma unroll
        for (int e = 0; e < 8; ++e) {
            u16 hh, ll;
            split2(T[ch * 16 + g * 8 + e][p], hh, ll);
            H[e] = (short)hh; L[e] = (short)ll;
        }
        *(s16x8*)(dhi + g * 8) = H;
        *(s16x8*)(dlo + g * 8) = L;
    }
}

// ---------------------------------------------------------------------------
// QKV projection, split-bf16 MFMA (validated core). Q pre-scale includes
// LOG2E (exp2-domain softmax). Epilogue Q/K branch now uses packed cvt.
// ---------------------------------------------------------------------------
__global__ __launch_bounds__(256, 4)
void gemm_qkv_mfma(const u16* __restrict__ Whi, const u16* __restrict__ Wlo,
                   const u16* __restrict__ Xhi, const u16* __restrict__ Xlo,
                   u16* __restrict__ qkt, u16* __restrict__ vd)
{
    __shared__ __align__(16) char smem[32768];
    u16* Ah = (u16*)smem;
    u16* Al = (u16*)(smem + 8192);
    u16* Bh = (u16*)(smem + 16384);
    u16* Bl = (u16*)(smem + 24576);

    const int t = threadIdx.x;
    const int lane = t & 63, w = t >> 6;
    const int lr = lane & 15, lq = lane >> 4;
    const int p0 = blockIdx.x * 64;
    const int m0 = blockIdx.y * 64;
    const int b  = blockIdx.z;
    const int row = t >> 2, ch = t & 3;

    const u16* wh = Whi + (size_t)(m0 + row) * CIN + ch * 16;
    const u16* wl = Wlo + (size_t)(m0 + row) * CIN + ch * 16;
    const u16* xh = Xhi + ((size_t)b * NTOK + p0 + row) * CIN + ch * 16;
    const u16* xl = Xlo + ((size_t)b * NTOK + p0 + row) * CIN + ch * 16;

    f32x4 acc[4] = {};
    for (int kc = 0; kc < CIN; kc += 64) {
        __syncthreads();
        st32(Ah, row, ch, *(const s16x8*)(wh + kc), *(const s16x8*)(wh + kc + 8));
        st32(Al, row, ch, *(const s16x8*)(wl + kc), *(const s16x8*)(wl + kc + 8));
        st32(Bh, row, ch, *(const s16x8*)(xh + kc), *(const s16x8*)(xh + kc + 8));
        st32(Bl, row, ch, *(const s16x8*)(xl + kc), *(const s16x8*)(xl + kc + 8));
        __syncthreads();
        #pragma unroll
        for (int ks = 0; ks < 2; ++ks) {
            const s16x8 ah = ldf(Ah, w * 16 + lr, ks * 4 + lq);
            const s16x8 al = ldf(Al, w * 16 + lr, ks * 4 + lq);
            #pragma unroll
            for (int js = 0; js < 4; ++js) {
                const s16x8 bh = ldf(Bh, js * 16 + lr, ks * 4 + lq);
                const s16x8 bl = ldf(Bl, js * 16 + lr, ks * 4 + lq);
                acc[js] = __builtin_amdgcn_mfma_f32_16x16x32_bf16(ah, bh, acc[js], 0, 0, 0);
                acc[js] = __builtin_amdgcn_mfma_f32_16x16x32_bf16(al, bh, acc[js], 0, 0, 0);
                acc[js] = __builtin_amdgcn_mfma_f32_16x16x32_bf16(ah, bl, acc[js], 0, 0, 0);
            }
        }
    }

    __syncthreads();
    u16* T = Ah;
    char* Tc = (char*)T;
    if (m0 < 1024) {
        const float scale = (m0 < 512) ? ATT_SCALE * LOG2E : 1.0f;  // exp2 domain
        #pragma unroll
        for (int js = 0; js < 4; ++js) {
            const int p = js * 16 + lr;
            const int base = p * 128 + (w * 16 + lq * 4) * 2;       // 8B aligned
            const unsigned w01 = cvtpk(acc[js][0] * scale, acc[js][1] * scale);
            const unsigned w23 = cvtpk(acc[js][2] * scale, acc[js][3] * scale);
            *(unsigned*)(Tc + ((base)     ^ ((p & 7) << 4))) = w01;
            *(unsigned*)(Tc + ((base + 4) ^ ((p & 7) << 4))) = w23;
        }
        __syncthreads();
        const int sidx = (m0 < 512) ? 0 : 1;
        const int h = (m0 & 511) >> 6;
        u16* dst = qkt + ((((size_t)b * 2 + sidx) * NH + h) * NTOK + p0 + row) * 64 + ch * 16;
        *(s16x8*)dst       = *(const s16x8*)(Tc + ((row * 128 + ch * 32)      ^ ((row & 7) << 4)));
        *(s16x8*)(dst + 8) = *(const s16x8*)(Tc + ((row * 128 + ch * 32 + 16) ^ ((row & 7) << 4)));
    } else {
        const int h = (m0 - 1024) >> 6;
        #pragma unroll
        for (int js = 0; js < 4; ++js) {
            const int p = js * 16 + lr;
            #pragma unroll
            for (int r = 0; r < 4; ++r) {
                const int o = w * 16 + lq * 4 + r;
                *(u16*)(Tc + ((o * 128 + p * 2) ^ ((o & 7) << 4))) = f2bf(acc[js][r]);
            }
        }
        __syncthreads();
        u16* dst = vd + (((size_t)b * NH + h) * 64 + row) * NTOK + p0 + ch * 16;
        *(s16x8*)dst       = *(const s16x8*)(Tc + ((row * 128 + ch * 32)      ^ ((row & 7) << 4)));
        *(s16x8*)(dst + 8) = *(const s16x8*)(Tc + ((row * 128 + ch * 32 + 16) ^ ((row & 7) << 4)));
    }
}

// ---------------------------------------------------------------------------
// Flash attention — round-9 structure (KVBLK=64, 32KB LDS, 4 blocks/CU),
// Q-fragment hoist, defer-max (THR=8, log2 domain), raw v_exp_f32,
// P conversion via packed v_cvt_pk_bf16_f32 (8 insts for 16 values).
// ---------------------------------------------------------------------------
__global__ __launch_bounds__(256, 4)
void attn_kernel(const u16* __restrict__ qkt, const u16* __restrict__ vd,
                 float* __restrict__ attn_out)
{
    __shared__ __align__(16) u16 Qt[64 * 64];
    __shared__ __align__(16) u16 Kt[64 * 64];
    __shared__ __align__(16) u16 Vt[64 * 64];
    __shared__ __align__(16) u16 Ps[64 * 64];

    const int t    = threadIdx.x;
    const int lane = t & 63;
    const int w    = t >> 6;
    const int lr   = lane & 15;
    const int lq   = lane >> 4;

    const int bid     = blockIdx.x;
    const int logical = (bid & 7) * 128 + (bid >> 3);
    const int it = logical & 15;
    const int h  = (logical >> 4) & 7;
    const int b  = logical >> 7;
    const int i0 = it * 64;

    const int srow = t >> 2, sch = t & 3;
    const u16* qg = qkt + ((((size_t)b * 2 + 0) * NH + h) * NTOK + i0 + srow) * 64 + sch * 8;
    const u16* kg = qkt + ((((size_t)b * 2 + 1) * NH + h) * NTOK + srow) * 64 + sch * 8;
    const u16* vg = vd  + (((size_t)b * NH + h) * 64 + srow) * NTOK + sch * 8;

    st_stage(Qt, t, *(const s16x8*)qg, *(const s16x8*)(qg + 32));

    s16x8 k0 = *(const s16x8*)kg, k1 = *(const s16x8*)(kg + 32);
    s16x8 v0 = *(const s16x8*)vg, v1 = *(const s16x8*)(vg + 32);

    // ---- Q-fragment hoist: constant across all 16 j-tiles ----
    __syncthreads();
    const s16x8 qb0 = ldf(Qt, w * 16 + lr, lq);
    const s16x8 qb1 = ldf(Qt, w * 16 + lr, 4 + lq);

    f32x4 o0 = {0.f,0.f,0.f,0.f}, o1 = o0, o2 = o0, o3 = o0;
    float m_run = -INFINITY, l_run = 0.0f;

    const int ii = w * 16 + lr;            // this lane's query row
    char* pr = (char*)Ps;

    for (int jt = 0; jt < 16; ++jt) {
        __syncthreads();                       // prior tile's LDS reads done
        st_stage(Kt, t, k0, k1);
        st_stage(Vt, t, v0, v1);
        const int jn = (jt + 1) & 15;          // prefetch next tile (wraps; L2-hot)
        k0 = *(const s16x8*)(kg + (size_t)jn * 4096);
        k1 = *(const s16x8*)(kg + (size_t)jn * 4096 + 32);
        v0 = *(const s16x8*)(vg + (size_t)jn * 64);
        v1 = *(const s16x8*)(vg + (size_t)jn * 64 + 32);
        __syncthreads();                       // K/V tiles ready

        // ---- S^T tile: A = K rows j, B = Q rows i (log2 domain) ----
        f32x4 s0 = {0.f,0.f,0.f,0.f}, s1 = s0, s2 = s0, s3 = s0;
        s0 = __builtin_amdgcn_mfma_f32_16x16x32_bf16(ldf(Kt,      lr, lq), qb0, s0, 0,0,0);
        s1 = __builtin_amdgcn_mfma_f32_16x16x32_bf16(ldf(Kt, 16 + lr, lq), qb0, s1, 0,0,0);
        s2 = __builtin_amdgcn_mfma_f32_16x16x32_bf16(ldf(Kt, 32 + lr, lq), qb0, s2, 0,0,0);
        s3 = __builtin_amdgcn_mfma_f32_16x16x32_bf16(ldf(Kt, 48 + lr, lq), qb0, s3, 0,0,0);
        s0 = __builtin_amdgcn_mfma_f32_16x16x32_bf16(ldf(Kt,      lr, 4 + lq), qb1, s0, 0,0,0);
        s1 = __builtin_amdgcn_mfma_f32_16x16x32_bf16(ldf(Kt, 16 + lr, 4 + lq), qb1, s1, 0,0,0);
        s2 = __builtin_amdgcn_mfma_f32_16x16x32_bf16(ldf(Kt, 32 + lr, 4 + lq), qb1, s2, 0,0,0);
        s3 = __builtin_amdgcn_mfma_f32_16x16x32_bf16(ldf(Kt, 48 + lr, 4 + lq), qb1, s3, 0,0,0);

        // ---- online softmax, defer-max: rescale only when max grew > 8 ----
        float mt = fmaxf(fmaxf(hmax4(s0), hmax4(s1)), fmaxf(hmax4(s2), hmax4(s3)));
        mt = fmaxf(mt, __shfl_xor(mt, 16));
        mt = fmaxf(mt, __shfl_xor(mt, 32));
        if (!__all(mt - m_run <= 8.0f)) {
            const float mnew = fmaxf(m_run, mt);
            const float corr = __builtin_amdgcn_exp2f(m_run - mnew);
            l_run *= corr;
            o0 *= corr; o1 *= corr; o2 *= corr; o3 *= corr;
            m_run = mnew;
        }
        f32x4 p0v, p1v, p2v, p3v;
        #pragma unroll
        for (int r = 0; r < 4; ++r) {
            p0v[r] = __builtin_amdgcn_exp2f(s0[r] - m_run);
            p1v[r] = __builtin_amdgcn_exp2f(s1[r] - m_run);
            p2v[r] = __builtin_amdgcn_exp2f(s2[r] - m_run);
            p3v[r] = __builtin_amdgcn_exp2f(s3[r] - m_run);
        }
        float lt = (hsum4(p0v) + hsum4(p1v)) + (hsum4(p2v) + hsum4(p3v));
        lt += __shfl_xor(lt, 16);
        lt += __shfl_xor(lt, 32);
        l_run += lt;

        // ---- P writes: packed cvt (v_cvt_pk_bf16_f32), same addresses ----
        {
            u32x2 a = { cvtpk(p0v[0], p0v[1]), cvtpk(p0v[2], p0v[3]) };
            u32x2 bq= { cvtpk(p1v[0], p1v[1]), cvtpk(p1v[2], p1v[3]) };
            u32x2 c = { cvtpk(p2v[0], p2v[1]), cvtpk(p2v[2], p2v[3]) };
            u32x2 d = { cvtpk(p3v[0], p3v[1]), cvtpk(p3v[2], p3v[3]) };
            *(u32x2*)(pr + ((ii * 128 + ( 0 + lq * 4) * 2) ^ ((ii & 7) << 4))) = a;
            *(u32x2*)(pr + ((ii * 128 + (16 + lq * 4) * 2) ^ ((ii & 7) << 4))) = bq;
            *(u32x2*)(pr + ((ii * 128 + (32 + lq * 4) * 2) ^ ((ii & 7) << 4))) = c;
            *(u32x2*)(pr + ((ii * 128 + (48 + lq * 4) * 2) ^ ((ii & 7) << 4))) = d;
        }

        // ---- PV: O^T[d][i] += V[d][j] * P[i][j] (wave-local Ps rows) ----
        #pragma unroll
        for (int ks = 0; ks < 2; ++ks) {
            const s16x8 pb = ldf(Ps, w * 16 + lr, ks * 4 + lq);
            o0 = __builtin_amdgcn_mfma_f32_16x16x32_bf16(ldf(Vt,      lr, ks*4+lq), pb, o0, 0,0,0);
            o1 = __builtin_amdgcn_mfma_f32_16x16x32_bf16(ldf(Vt, 16 + lr, ks*4+lq), pb, o1, 0,0,0);
            o2 = __builtin_amdgcn_mfma_f32_16x16x32_bf16(ldf(Vt, 32 + lr, ks*4+lq), pb, o2, 0,0,0);
            o3 = __builtin_amdgcn_mfma_f32_16x16x32_bf16(ldf(Vt, 48 + lr, ks*4+lq), pb, o3, 0,0,0);
        }
    }

    // ---- normalize (lane-local 1/l) and store O^T[d][i] fp32 ----
    const float inv = 1.0f / l_run;
    float* og = attn_out + (((size_t)b * NH + h) * 64) * NTOK + i0 + w * 16 + lr;
    #pragma unroll
    for (int r = 0; r < 4; ++r) {
        og[(size_t)( 0 + lq * 4 + r) * NTOK] = o0[r] * inv;
        og[(size_t)(16 + lq * 4 + r) * NTOK] = o1[r] * inv;
        og[(size_t)(32 + lq * 4 + r) * NTOK] = o2[r] * inv;
        og[(size_t)(48 + lq * 4 + r) * NTOK] = o3[r] * inv;
    }
}

// ---------------------------------------------------------------------------
// Output projection, split-bf16 MFMA; B-staging converts via packed cvt.
// ---------------------------------------------------------------------------
__global__ __launch_bounds__(256, 4)
void gemm_out_mfma(const u16* __restrict__ Whi, const u16* __restrict__ Wlo,
                   const float* __restrict__ attn, const float* __restrict__ bias,
                   float* __restrict__ out)
{
    __shared__ __align__(16) char smem[24576];
    u16* Ah = (u16*)smem;
    u16* Al = (u16*)(smem + 8192);
    u16* Bt = (u16*)(smem + 16384);

    const int t = threadIdx.x;
    const int lane = t & 63, w = t >> 6;
    const int lr = lane & 15, lq = lane >> 4;
    const int p0 = blockIdx.x * 64;
    const int m0 = blockIdx.y * 64;
    const int b  = blockIdx.z;
    const int row = t >> 2, ch = t & 3;

    const u16* wh = Whi + (size_t)(m0 + row) * HIDDEN + ch * 16;
    const u16* wl = Wlo + (size_t)(m0 + row) * HIDDEN + ch * 16;
    const float* ab = attn + (size_t)b * HIDDEN * NTOK + p0;
    const int btok = t & 63;          // token row of Bt this thread stages
    const int bog  = (t >> 6) * 16;   // 16 o-columns per wave

    f32x4 acc[4] = {};
    for (int kc = 0; kc < HIDDEN; kc += 64) {
        __syncthreads();
        st32(Ah, row, ch, *(const s16x8*)(wh + kc), *(const s16x8*)(wh + kc + 8));
        st32(Al, row, ch, *(const s16x8*)(wl + kc), *(const s16x8*)(wl + kc + 8));
        // B: transpose-convert fp32 [o][tok] -> bf16 Bt[tok][o] (packed cvt)
        {
            const float* col = ab + btok;
            u32x4v W0, W1;
            #pragma unroll
            for (int q = 0; q < 4; ++q)
                W0[q] = cvtpk(col[(size_t)(kc + bog + 2 * q) * NTOK],
                              col[(size_t)(kc + bog + 2 * q + 1) * NTOK]);
            #pragma unroll
            for (int q = 0; q < 4; ++q)
                W1[q] = cvtpk(col[(size_t)(kc + bog + 8 + 2 * q) * NTOK],
                              col[(size_t)(kc + bog + 8 + 2 * q + 1) * NTOK]);
            char* bp = (char*)Bt;
            *(u32x4v*)(bp + ((btok * 128 + bog * 2)      ^ ((btok & 7) << 4))) = W0;
            *(u32x4v*)(bp + ((btok * 128 + bog * 2 + 16) ^ ((btok & 7) << 4))) = W1;
        }
        __syncthreads();
        #pragma unroll
        for (int ks = 0; ks < 2; ++ks) {
            const s16x8 ah = ldf(Ah, w * 16 + lr, ks * 4 + lq);
            const s16x8 al = ldf(Al, w * 16 + lr, ks * 4 + lq);
            #pragma unroll
            for (int js = 0; js < 4; ++js) {
                const s16x8 bh = ldf(Bt, js * 16 + lr, ks * 4 + lq);
                acc[js] = __builtin_amdgcn_mfma_f32_16x16x32_bf16(ah, bh, acc[js], 0, 0, 0);
                acc[js] = __builtin_amdgcn_mfma_f32_16x16x32_bf16(al, bh, acc[js], 0, 0, 0);
            }
        }
    }

    __syncthreads();
    float* T = (float*)smem;              // 64*68*4 = 17408 B < 24576
    #pragma unroll
    for (int js = 0; js < 4; ++js) {
        const int p = js * 16 + lr;
        #pragma unroll
        for (int r = 0; r < 4; ++r)
            T[(w * 16 + lq * 4 + r) * 68 + p] = acc[js][r];
    }
    __syncthreads();
    const float bv = bias[m0 + row];
    float* dst = out + ((size_t)b * CIN + m0 + row) * NTOK + p0;
    #pragma unroll
    for (int q = 0; q < 4; ++q) {
        float4 v = *(const float4*)&T[row * 68 + ch * 4 + q * 16];
        v.x += bv; v.y += bv; v.z += bv; v.w += bv;
        *(float4*)&dst[ch * 4 + q * 16] = v;
    }
}

// ---------------------------------------------------------------------------
extern "C" void kernel_launch(void* const* d_in, const int* in_sizes, int n_in,
                              void* d_out, int out_size, void* d_ws, size_t ws_size,
                              hipStream_t stream)
{
    const float* x    = (const float*)d_in[0];   // [8][256][1024]
    const float* Wqkv = (const float*)d_in[1];   // [1536][256]
    const float* Wout = (const float*)d_in[2];   // [256][512]
    const float* bout = (const float*)d_in[3];   // [256]
    float* out = (float*)d_out;                  // [8][256][1024]

    char* ws = (char*)d_ws;
    u16* Wqhi = (u16*)ws;                         ws += (size_t)O3 * CIN * 2;
    u16* Wqlo = (u16*)ws;                         ws += (size_t)O3 * CIN * 2;
    u16* Wohi = (u16*)ws;                         ws += (size_t)CIN * HIDDEN * 2;
    u16* Wolo = (u16*)ws;                         ws += (size_t)CIN * HIDDEN * 2;
    u16* xThi = (u16*)ws;                         ws += (size_t)BATCH * NTOK * CIN * 2;
    u16* xTlo = (u16*)ws;                         ws += (size_t)BATCH * NTOK * CIN * 2;
    u16* qkt  = (u16*)ws;                         ws += (size_t)BATCH * 2 * NH * NTOK * HD * 2;
    u16* vd   = (u16*)ws;                         ws += (size_t)BATCH * NH * HD * NTOK * 2;
    float* attn = (float*)ws;                     ws += (size_t)BATCH * HIDDEN * NTOK * 4;

    const int n4A = O3 * CIN / 4, n4B = CIN * HIDDEN / 4;
    split_both<<<dim3((n4A + n4B + 255) / 256), 256, 0, stream>>>(
        Wqkv, Wqhi, Wqlo, n4A, Wout, Wohi, Wolo, n4B);
    xpose_x<<<dim3(16, 4, BATCH), 256, 0, stream>>>(x, xThi, xTlo);

    gemm_qkv_mfma<<<dim3(16, 24, BATCH), 256, 0, stream>>>(Wqhi, Wqlo, xThi, xTlo, qkt, vd);
    attn_kernel<<<dim3(1024), 256, 0, stream>>>(qkt, vd, attn);
    gemm_out_mfma<<<dim3(16, 4, BATCH), 256, 0, stream>>>(Wohi, Wolo, attn, bout, out);
}